// Round 3
// baseline (910.104 us; speedup 1.0000x reference)
//
#include <hip/hip_runtime.h>
#include <hip/hip_cooperative_groups.h>
#include <math.h>

namespace cg = cooperative_groups;

// JCPOT Sinkhorn. d_out: [0]=loss, [1..16M]=coupling, [1+16M..]=C.
// Primary path: GEMM writes C only; ONE cooperative kernel holds K (fp16) in LDS
// (16 rows x 4096 per block, 256 blocks) and runs all 10 Sinkhorn iterations with
// grid syncs + fused coupling/loss tail. Fallbacks: round-2 pipeline, then round-1.

#define N_S 4096
#define N_T 4096
#define DIM 512
#define STAB 1e-8f

typedef _Float16 f16x2 __attribute__((ext_vector_type(2)));
typedef _Float16 f16x4 __attribute__((ext_vector_type(4)));
typedef _Float16 f16x8 __attribute__((ext_vector_type(8)));
typedef float f32x4v __attribute__((ext_vector_type(4)));

#define COOP_SMEM (131072 + 64 + 512 + 2048)

// ---------- row squared norms ----------
__global__ __launch_bounds__(256) void k_norms(const float4* __restrict__ S4,
                                               const float4* __restrict__ T4,
                                               float* __restrict__ ns, float* __restrict__ nt) {
    int t = threadIdx.x;
    int lane = t & 63, wave = t >> 6;
    int wid = blockIdx.x * 4 + wave;
    const float4* src; float* dst; int row;
    if (wid < N_S) { src = S4; dst = ns; row = wid; }
    else           { src = T4; dst = nt; row = wid - N_S; }
    float acc = 0.f;
#pragma unroll
    for (int c = 0; c < 2; ++c) {
        float4 x = src[row * 128 + c * 64 + lane];
        acc += x.x*x.x + x.y*x.y + x.z*x.z + x.w*x.w;
    }
#pragma unroll
    for (int m = 32; m; m >>= 1) acc += __shfl_xor(acc, m);
    if (lane == 0) dst[row] = acc;
}

__global__ void k_init(float* v, float* vacc, double* lossd) {
    int g = blockIdx.x * 256 + threadIdx.x;
    if (g < N_T) { v[g] = 1.0f; vacc[g] = 0.0f; }
    if (g == 0) *lossd = 0.0;
}

// ---------- GEMM (f16 MFMA): MODE 0: fp32 K + C; MODE 1: fp16 Kh + C; MODE 2: C only ----------
template<int MODE>
__global__ __launch_bounds__(256) void k_gemm(const float* __restrict__ S, const float* __restrict__ T,
                                              const float* __restrict__ ns, const float* __restrict__ nt,
                                              float* __restrict__ outK, _Float16* __restrict__ outKh,
                                              float* __restrict__ outC) {
    __shared__ _Float16 As[128 * 40];
    __shared__ _Float16 Bs[128 * 40];
    int t = threadIdx.x;
    int lane = t & 63, wave = t >> 6;
    int wr = wave >> 1, wc = wave & 1;
    int brow = blockIdx.x * 128, bcol = blockIdx.y * 128;

    f32x4v acc[4][4] = {};

    for (int kt = 0; kt < DIM; kt += 32) {
        __syncthreads();
#pragma unroll
        for (int w = 0; w < 4; ++w) {
            int e = w * 1024 + t * 4;
            int row = e >> 5, col = e & 31;
            float4 a = *(const float4*)(S + (size_t)(brow + row) * DIM + kt + col);
            f16x4 ah = { (_Float16)a.x, (_Float16)a.y, (_Float16)a.z, (_Float16)a.w };
            *(f16x4*)(&As[row * 40 + col]) = ah;
            float4 b = *(const float4*)(T + (size_t)(bcol + row) * DIM + kt + col);
            f16x4 bh = { (_Float16)b.x, (_Float16)b.y, (_Float16)b.z, (_Float16)b.w };
            *(f16x4*)(&Bs[row * 40 + col]) = bh;
        }
        __syncthreads();

        f16x8 af[4], bf[4];
#pragma unroll
        for (int m = 0; m < 4; ++m)
            af[m] = *(const f16x8*)(&As[(wr * 64 + m * 16 + (lane & 15)) * 40 + (lane >> 4) * 8]);
#pragma unroll
        for (int n = 0; n < 4; ++n)
            bf[n] = *(const f16x8*)(&Bs[(wc * 64 + n * 16 + (lane & 15)) * 40 + (lane >> 4) * 8]);
#pragma unroll
        for (int m = 0; m < 4; ++m)
#pragma unroll
            for (int n = 0; n < 4; ++n)
                acc[m][n] = __builtin_amdgcn_mfma_f32_16x16x32_f16(af[m], bf[n], acc[m][n], 0, 0, 0);
    }

#pragma unroll
    for (int m = 0; m < 4; ++m) {
#pragma unroll
        for (int n = 0; n < 4; ++n) {
#pragma unroll
            for (int r = 0; r < 4; ++r) {
                int i = brow + wr * 64 + m * 16 + (lane >> 4) * 4 + r;
                int j = bcol + wc * 64 + n * 16 + (lane & 15);
                float dot = acc[m][n][r];
                float sq = ns[i] + nt[j] - 2.0f * dot;
                float c = sqrtf(fmaxf(sq, 0.0f));
                size_t idx = (size_t)i * N_T + j;
                outC[idx] = c;
                if constexpr (MODE == 0) outK[idx] = __expf(-c * 0.125f);
                if constexpr (MODE == 1) outKh[idx] = (_Float16)__expf(-c * 0.125f);
            }
        }
    }
}

// ---------- cooperative: whole Sinkhorn loop with LDS-resident K, fused final ----------
__global__ __launch_bounds__(512, 1) void k_coop(const float* __restrict__ Cd,
                                                 float* __restrict__ W,
                                                 float* __restrict__ part,
                                                 float* __restrict__ v,
                                                 double* __restrict__ lossd) {
    cg::grid_group grid = cg::this_grid();
    extern __shared__ char smem[];
    _Float16* Ksh = (_Float16*)smem;                   // [16][4096] = 128 KB
    float* u_s  = (float*)(smem + 131072);             // 16
    float* wred = (float*)(smem + 131072 + 64);        // [8 waves][16 rows]
    float* cred = (float*)(smem + 131072 + 64 + 512);  // [32][16]

    const int t = threadIdx.x;
    const int lane = t & 63, wave = t >> 6;
    const int b = blockIdx.x;
    const int base = t * 8;                            // 8 cols per thread

    const float* Crow = Cd + (size_t)b * (16 * 4096);

    // load C -> K = exp(-C/8) into LDS (fp16)
#pragma unroll
    for (int i = 0; i < 16; ++i) {
        const float* cp = Crow + i * 4096 + base;
        float4 c0 = *(const float4*)cp;
        float4 c1 = *(const float4*)(cp + 4);
        f16x8 h;
        h[0] = (_Float16)__expf(c0.x * -0.125f);
        h[1] = (_Float16)__expf(c0.y * -0.125f);
        h[2] = (_Float16)__expf(c0.z * -0.125f);
        h[3] = (_Float16)__expf(c0.w * -0.125f);
        h[4] = (_Float16)__expf(c1.x * -0.125f);
        h[5] = (_Float16)__expf(c1.y * -0.125f);
        h[6] = (_Float16)__expf(c1.z * -0.125f);
        h[7] = (_Float16)__expf(c1.w * -0.125f);
        *(f16x8*)(Ksh + i * 4096 + base) = h;
    }
    __syncthreads();

    for (int it = 0; it < 10; ++it) {
        // ---- row pass: u = a / (K v) ----
        float4 v0 = *(const float4*)(v + base);
        float4 v1 = *(const float4*)(v + base + 4);
        float vf[8] = {v0.x, v0.y, v0.z, v0.w, v1.x, v1.y, v1.z, v1.w};
#pragma unroll
        for (int i = 0; i < 16; ++i) {
            f16x8 k8 = *(const f16x8*)(Ksh + i * 4096 + base);
            float p = 0.f;
#pragma unroll
            for (int c = 0; c < 8; ++c) p += (float)k8[c] * vf[c];
#pragma unroll
            for (int m = 32; m; m >>= 1) p += __shfl_xor(p, m);
            if (lane == 0) wred[wave * 16 + i] = p;
        }
        __syncthreads();
        if (t < 16) {
            float s = 0.f;
#pragma unroll
            for (int w = 0; w < 8; ++w) s += wred[w * 16 + t];
            u_s[t] = (1.0f / N_S) / (s + STAB);
        }
        __syncthreads();
        // ---- col pass: per-block column partials ----
        float acc[8] = {0.f,0.f,0.f,0.f,0.f,0.f,0.f,0.f};
#pragma unroll
        for (int i = 0; i < 16; ++i) {
            f16x8 k8 = *(const f16x8*)(Ksh + i * 4096 + base);
            float ui = u_s[i];
#pragma unroll
            for (int c = 0; c < 8; ++c) acc[c] += ui * (float)k8[c];
        }
        float* pp = part + (size_t)b * 4096 + base;
        *(float4*)pp       = make_float4(acc[0], acc[1], acc[2], acc[3]);
        *(float4*)(pp + 4) = make_float4(acc[4], acc[5], acc[6], acc[7]);
        grid.sync();
        // ---- distributed v-reduce: block b owns cols [b*16, b*16+16) ----
        {
            int c = t & 15, p0 = t >> 4;               // 32 chunks x 8 partials
            int j = b * 16 + c;
            float s = 0.f;
#pragma unroll
            for (int k = 0; k < 8; ++k)
                s += part[(size_t)(p0 * 8 + k) * 4096 + j];
            cred[p0 * 16 + c] = s;
        }
        __syncthreads();
        if (t < 16) {
            float s2 = 0.f;
#pragma unroll
            for (int k = 0; k < 32; ++k) s2 += cred[k * 16 + t];
            v[b * 16 + t] = (1.0f / N_T) / (s2 + STAB);
        }
        grid.sync();
    }

    // ---- fused final: W = u*K*v, loss += sum(W*C), C recovered as -8*ln(K) ----
    float4 v0 = *(const float4*)(v + base);
    float4 v1 = *(const float4*)(v + base + 4);
    float vf[8] = {v0.x, v0.y, v0.z, v0.w, v1.x, v1.y, v1.z, v1.w};
    float lacc = 0.f;
    const float NEG8LN2 = -5.5451774444795623f;        // -8*ln(2)
#pragma unroll
    for (int i = 0; i < 16; ++i) {
        f16x8 k8 = *(const f16x8*)(Ksh + i * 4096 + base);
        float ui = u_s[i];
        float w[8];
#pragma unroll
        for (int c = 0; c < 8; ++c) {
            float kf = (float)k8[c];
            float wc = ui * kf * vf[c];
            w[c] = wc;
            lacc += wc * (NEG8LN2 * __log2f(kf));
        }
        float* wp = W + (size_t)(b * 16 + i) * 4096 + base;
        *(float4*)wp       = make_float4(w[0], w[1], w[2], w[3]);
        *(float4*)(wp + 4) = make_float4(w[4], w[5], w[6], w[7]);
    }
#pragma unroll
    for (int m = 32; m; m >>= 1) lacc += __shfl_xor(lacc, m);
    if (lane == 0) wred[wave] = lacc;
    __syncthreads();
    if (t == 0) {
        float s = 0.f;
#pragma unroll
        for (int w = 0; w < 8; ++w) s += wred[w];
        atomicAdd(lossd, (double)s);
    }
}

__global__ void k_loss(const double* __restrict__ lossd, float* __restrict__ out0) {
    *out0 = (float)(*lossd / ((double)N_S * (double)N_T));
}

// ================= fallback: Kh = exp(-C/8) from C =================
__global__ __launch_bounds__(256) void k_kh(const float* __restrict__ Cd, _Float16* __restrict__ Kh) {
    size_t i = ((size_t)blockIdx.x * 256 + threadIdx.x) * 8;
    float4 c0 = *(const float4*)(Cd + i);
    float4 c1 = *(const float4*)(Cd + i + 4);
    f16x8 h;
    h[0] = (_Float16)__expf(c0.x * -0.125f);
    h[1] = (_Float16)__expf(c0.y * -0.125f);
    h[2] = (_Float16)__expf(c0.z * -0.125f);
    h[3] = (_Float16)__expf(c0.w * -0.125f);
    h[4] = (_Float16)__expf(c1.x * -0.125f);
    h[5] = (_Float16)__expf(c1.y * -0.125f);
    h[6] = (_Float16)__expf(c1.z * -0.125f);
    h[7] = (_Float16)__expf(c1.w * -0.125f);
    *(f16x8*)(Kh + i) = h;
}

// ================= fallback (round-2 proven) kernels =================
__global__ __launch_bounds__(256) void k_sink(const _Float16* __restrict__ Kh,
                                              const float* __restrict__ v,
                                              float* __restrict__ u_out,
                                              float* __restrict__ part) {
    __shared__ _Float16 rows[4][4096];
    __shared__ float u_s[4];
    int t = threadIdx.x, lane = t & 63, w = t >> 6;
    float2 acc[8];
#pragma unroll
    for (int s = 0; s < 8; ++s) acc[s] = make_float2(0.f, 0.f);

    for (int c = 0; c < 2; ++c) {
        if (c) __syncthreads();
        int row = blockIdx.x * 8 + c * 4 + w;
        const _Float16* Kr = Kh + (size_t)row * N_T;
        float dot = 0.f;
#pragma unroll
        for (int it = 0; it < 8; ++it) {
            int j0 = it * 512 + lane * 8;
            f16x8 kv = *(const f16x8*)(Kr + j0);
            float4 v0 = *(const float4*)(v + j0);
            float4 v1 = *(const float4*)(v + j0 + 4);
            *(f16x8*)(&rows[w][j0]) = kv;
            dot += (float)kv[0]*v0.x + (float)kv[1]*v0.y + (float)kv[2]*v0.z + (float)kv[3]*v0.w
                 + (float)kv[4]*v1.x + (float)kv[5]*v1.y + (float)kv[6]*v1.z + (float)kv[7]*v1.w;
        }
#pragma unroll
        for (int m = 32; m; m >>= 1) dot += __shfl_xor(dot, m);
        if (lane == 0) {
            float uv = (1.0f / N_S) / (dot + STAB);
            u_s[w] = uv;
            u_out[row] = uv;
        }
        __syncthreads();
#pragma unroll
        for (int s = 0; s < 8; ++s) {
            int jj = t * 2 + s * 512;
#pragma unroll
            for (int r = 0; r < 4; ++r) {
                f16x2 kk = *(const f16x2*)(&rows[r][jj]);
                float uu = u_s[r];
                acc[s].x += uu * (float)kk[0];
                acc[s].y += uu * (float)kk[1];
            }
        }
    }
    float* pb = part + (size_t)blockIdx.x * N_T;
#pragma unroll
    for (int s = 0; s < 8; ++s)
        *(float2*)(pb + t * 2 + s * 512) = acc[s];
}

__global__ __launch_bounds__(256) void k_vfin2(const float* __restrict__ part, float* __restrict__ v) {
    __shared__ float sums[256];
    int t = threadIdx.x;
    int jl = t & 15, c = t >> 4;
    int j = blockIdx.x * 16 + jl;
    float acc = 0.f;
#pragma unroll 8
    for (int k = 0; k < 32; ++k)
        acc += part[(size_t)(c * 32 + k) * N_T + j];
    sums[t] = acc;
    __syncthreads();
    if (t < 16) {
        float s = 0.f;
#pragma unroll
        for (int c2 = 0; c2 < 16; ++c2) s += sums[c2 * 16 + t];
        v[blockIdx.x * 16 + t] = (1.0f / N_T) / (s + STAB);
    }
}

__global__ __launch_bounds__(256) void k_final2(const _Float16* __restrict__ Kh, const float* __restrict__ Cd,
                                                const float* __restrict__ u, const float* __restrict__ v,
                                                float* __restrict__ W, double* __restrict__ lossd) {
    int t = threadIdx.x, row = blockIdx.x;
    float ui = u[row];
    float lacc = 0.f;
    const _Float16* Kr = Kh + (size_t)row * N_T;
    const float* Cr = Cd + (size_t)row * N_T;
    float* Wr = W + (size_t)row * N_T;
#pragma unroll
    for (int cc = 0; cc < 4; ++cc) {
        int j = (cc * 256 + t) * 4;
        f16x4 kk = *(const f16x4*)(Kr + j);
        float4 c4 = *(const float4*)(Cr + j);
        float4 v4 = *(const float4*)(v + j);
        float4 w4;
        w4.x = ui * (float)kk[0] * v4.x;
        w4.y = ui * (float)kk[1] * v4.y;
        w4.z = ui * (float)kk[2] * v4.z;
        w4.w = ui * (float)kk[3] * v4.w;
        *(float4*)(Wr + j) = w4;
        lacc += w4.x*c4.x + w4.y*c4.y + w4.z*c4.z + w4.w*c4.w;
    }
#pragma unroll
    for (int m = 32; m; m >>= 1) lacc += __shfl_xor(lacc, m);
    __shared__ float wsum[4];
    int lane = t & 63, wave = t >> 6;
    if (lane == 0) wsum[wave] = lacc;
    __syncthreads();
    if (t == 0) atomicAdd(lossd, (double)(wsum[0] + wsum[1] + wsum[2] + wsum[3]));
}

// ================= fallback (round-1 proven, tiny ws) kernels =================
__global__ __launch_bounds__(256) void k_rowmv(const float* __restrict__ Kd,
                                               const float* __restrict__ v, float* __restrict__ u) {
    __shared__ float vl[4096];
    int t = threadIdx.x;
#pragma unroll
    for (int c = 0; c < 16; ++c) vl[c * 256 + t] = v[c * 256 + t];
    __syncthreads();
    int lane = t & 63, wave = t >> 6;
    int row = blockIdx.x * 4 + wave;
    const float* Kr = Kd + (size_t)row * N_T;
    float dot = 0.f;
#pragma unroll 8
    for (int c = 0; c < 64; ++c) {
        int j = c * 64 + lane;
        dot += Kr[j] * vl[j];
    }
#pragma unroll
    for (int m = 32; m; m >>= 1) dot += __shfl_xor(dot, m);
    if (lane == 0) u[row] = (1.0f / N_S) / (dot + STAB);
}

__global__ __launch_bounds__(256) void k_colmv(const float* __restrict__ Kd,
                                               const float* __restrict__ u, float* __restrict__ vacc) {
    __shared__ float ul[64];
    int t = threadIdx.x;
    int rc = blockIdx.y;
    if (t < 64) ul[t] = u[rc * 64 + t];
    __syncthreads();
    int j = blockIdx.x * 256 + t;
    const float* Kp = Kd + (size_t)(rc * 64) * N_T + j;
    float acc = 0.f;
#pragma unroll 8
    for (int r = 0; r < 64; ++r) acc += Kp[(size_t)r * N_T] * ul[r];
    atomicAdd(&vacc[j], acc);
}

__global__ void k_vfin(float* v, float* vacc) {
    int j = blockIdx.x * 256 + threadIdx.x;
    v[j] = (1.0f / N_T) / (vacc[j] + STAB);
    vacc[j] = 0.f;
}

__global__ __launch_bounds__(256) void k_final(float* __restrict__ Kd, const float* __restrict__ Cd,
                                               const float* __restrict__ u, const float* __restrict__ v,
                                               double* __restrict__ lossd) {
    int t = threadIdx.x;
    int row = blockIdx.x;
    float ui = u[row];
    float lacc = 0.f;
#pragma unroll 4
    for (int c = 0; c < 16; ++c) {
        int j = c * 256 + t;
        size_t idx = (size_t)row * N_T + j;
        float w = ui * Kd[idx] * v[j];
        Kd[idx] = w;
        lacc += w * Cd[idx];
    }
#pragma unroll
    for (int m = 32; m; m >>= 1) lacc += __shfl_xor(lacc, m);
    __shared__ float wsum[4];
    int lane = t & 63, wave = t >> 6;
    if (lane == 0) wsum[wave] = lacc;
    __syncthreads();
    if (t == 0) atomicAdd(lossd, (double)(wsum[0] + wsum[1] + wsum[2] + wsum[3]));
}

// =====================================================================
extern "C" void kernel_launch(void* const* d_in, const int* in_sizes, int n_in,
                              void* d_out, int out_size, void* d_ws, size_t ws_size,
                              hipStream_t stream) {
    const float* S = (const float*)d_in[0];
    const float* T = (const float*)d_in[1];
    float* out = (float*)d_out;
    float* outCoup = out + 1;
    float* outC = out + 1 + (size_t)N_S * N_T;

    const size_t MB = 1024 * 1024;
    // layout (proven-capacity packing): [0,32M)=kh(fallback)/partC(coop, first 4M)
    //                                   [32M,40M)=part8(fallback)  [40M,+64K+8)=scalars
    const size_t need = 40 * MB + 64 * 1024 + 16;

    if (ws_size >= need) {
        char* wsb = (char*)d_ws;
        float* partC   = (float*)wsb;                 // coop partials [256][4096]
        _Float16* kh   = (_Float16*)wsb;              // fallback Kh (aliases partC; exclusive paths)
        float* part8   = (float*)(wsb + 32 * MB);     // fallback k_sink partials [512][4096]
        float* ns = (float*)(wsb + 40 * MB);
        float* nt = ns + 4096;
        float* u  = nt + 4096;
        float* v  = u + 4096;
        double* lossd = (double*)(v + 4096);

        k_norms<<<2048, 256, 0, stream>>>((const float4*)S, (const float4*)T, ns, nt);
        k_init<<<16, 256, 0, stream>>>(v, partC, lossd);
        k_gemm<2><<<dim3(32, 32), 256, 0, stream>>>(S, T, ns, nt, nullptr, nullptr, outC);

        (void)hipFuncSetAttribute((const void*)k_coop,
                                  hipFuncAttributeMaxDynamicSharedMemorySize, COOP_SMEM);
        const float* CdArg = outC; float* WArg = outCoup; float* partArg = partC;
        float* vArg = v; double* ldArg = lossd;
        void* args[5] = { &CdArg, &WArg, &partArg, &vArg, &ldArg };
        hipError_t ce = hipLaunchCooperativeKernel((const void*)k_coop, dim3(256), dim3(512),
                                                   args, (unsigned)COOP_SMEM, stream);
        if (ce == hipSuccess) {
            k_loss<<<1, 1, 0, stream>>>(lossd, out);
        } else {
            // proven round-2 pipeline: materialize Kh from C, then k_sink loop
            k_kh<<<8192, 256, 0, stream>>>(outC, kh);
            for (int it = 0; it < 10; ++it) {
                k_sink<<<512, 256, 0, stream>>>(kh, v, u, part8);
                k_vfin2<<<256, 256, 0, stream>>>(part8, v);
            }
            k_final2<<<4096, 256, 0, stream>>>(kh, outC, u, v, outCoup, lossd);
            k_loss<<<1, 1, 0, stream>>>(lossd, out);
        }
    } else {
        // round-1 proven fallback: fp32 K staged in coupling slot, tiny ws
        float* outK = outCoup;
        float* ws   = (float*)d_ws;
        float* ns   = ws;
        float* nt   = ws + 4096;
        float* u    = ws + 8192;
        float* v    = ws + 12288;
        float* vacc = ws + 16384;
        double* lossd = (double*)(ws + 20480);

        k_norms<<<2048, 256, 0, stream>>>((const float4*)S, (const float4*)T, ns, nt);
        k_init<<<16, 256, 0, stream>>>(v, vacc, lossd);
        k_gemm<0><<<dim3(32, 32), 256, 0, stream>>>(S, T, ns, nt, outK, nullptr, outC);
        for (int it = 0; it < 10; ++it) {
            k_rowmv<<<1024, 256, 0, stream>>>(outK, v, u);
            k_colmv<<<dim3(16, 64), 256, 0, stream>>>(outK, u, vacc);
            k_vfin<<<16, 256, 0, stream>>>(v, vacc);
        }
        k_final<<<4096, 256, 0, stream>>>(outK, outC, u, v, lossd);
        k_loss<<<1, 1, 0, stream>>>(lossd, out);
    }
}

// Round 4
// 640.605 us; speedup vs baseline: 1.4207x; 1.4207x over previous
//
#include <hip/hip_runtime.h>
#include <math.h>

// JCPOT Sinkhorn. d_out: [0]=loss, [1..16M]=coupling, [1+16M..]=C.
// Main path: fp16-blocked GEMM writes C; ONE cooperative kernel holds K (fp16) in LDS
// (16 rows x 4096 per block, 256 blocks) runs all 10 Sinkhorn iterations using a
// HAND-ROLLED global barrier (cg::grid.sync measured ~34us/sync in round 3).
// Fallbacks: coop-launch-fail -> fp32-K round-1 pipeline; tiny ws -> round-1.

#define N_S 4096
#define N_T 4096
#define DIM 512
#define STAB 1e-8f

typedef _Float16 f16x4 __attribute__((ext_vector_type(4)));
typedef _Float16 f16x8 __attribute__((ext_vector_type(8)));
typedef float f32x4v __attribute__((ext_vector_type(4)));

#define COOP_SMEM (131072 + 64 + 512 + 2048)
#define NBLK 256

// ---------- hand-rolled grid barrier (counters zeroed by k_init each call) ----------
__device__ __forceinline__ void gbar(int* cnt) {
    __syncthreads();
    if (threadIdx.x == 0) {
        __hip_atomic_fetch_add(cnt, 1, __ATOMIC_RELEASE, __HIP_MEMORY_SCOPE_AGENT);
        while (__hip_atomic_load(cnt, __ATOMIC_ACQUIRE, __HIP_MEMORY_SCOPE_AGENT) < NBLK)
            __builtin_amdgcn_s_sleep(2);
    }
    __syncthreads();
}

// ---------- row squared norms ----------
__global__ __launch_bounds__(256) void k_norms(const float4* __restrict__ S4,
                                               const float4* __restrict__ T4,
                                               float* __restrict__ ns, float* __restrict__ nt) {
    int t = threadIdx.x;
    int lane = t & 63, wave = t >> 6;
    int wid = blockIdx.x * 4 + wave;
    const float4* src; float* dst; int row;
    if (wid < N_S) { src = S4; dst = ns; row = wid; }
    else           { src = T4; dst = nt; row = wid - N_S; }
    float acc = 0.f;
#pragma unroll
    for (int c = 0; c < 2; ++c) {
        float4 x = src[row * 128 + c * 64 + lane];
        acc += x.x*x.x + x.y*x.y + x.z*x.z + x.w*x.w;
    }
#pragma unroll
    for (int m = 32; m; m >>= 1) acc += __shfl_xor(acc, m);
    if (lane == 0) dst[row] = acc;
}

// ---------- fp32 -> fp16 K-tile-blocked convert: dst[k/32][row][k%32] ----------
__global__ __launch_bounds__(256) void k_cvt(const float* __restrict__ S, const float* __restrict__ T,
                                             _Float16* __restrict__ Sh2, _Float16* __restrict__ Th2) {
    int g = blockIdx.x * 256 + threadIdx.x;        // 0..524287
    const float* src; _Float16* dst;
    if (g < 262144) { src = S; dst = Sh2; }
    else            { src = T; dst = Th2; g -= 262144; }
    int row = g >> 6, cb = (g & 63) * 8;
    float4 x0 = *(const float4*)(src + (size_t)row * 512 + cb);
    float4 x1 = *(const float4*)(src + (size_t)row * 512 + cb + 4);
    f16x8 h = { (_Float16)x0.x, (_Float16)x0.y, (_Float16)x0.z, (_Float16)x0.w,
                (_Float16)x1.x, (_Float16)x1.y, (_Float16)x1.z, (_Float16)x1.w };
    *(f16x8*)(dst + ((size_t)(cb >> 5) * 4096 + row) * 32 + (cb & 31)) = h;
}

// ---------- init v=1, vacc=0, barrier counters=0, loss=0 ----------
__global__ void k_init(float* v, float* vacc, double* lossd, int* cnt) {
    int g = blockIdx.x * 256 + threadIdx.x;
    if (g < N_T) { v[g] = 1.0f; vacc[g] = 0.0f; }
    if (g < 32) cnt[g] = 0;
    if (g == 0) *lossd = 0.0;
}

// ---------- GEMM from fp16-blocked inputs, writes C only ----------
__global__ __launch_bounds__(256) void k_gemm16(const _Float16* __restrict__ Sh2,
                                                const _Float16* __restrict__ Th2,
                                                const float* __restrict__ ns,
                                                const float* __restrict__ nt,
                                                float* __restrict__ outC) {
    __shared__ _Float16 As[128 * 40];
    __shared__ _Float16 Bs[128 * 40];
    int t = threadIdx.x;
    int lane = t & 63, wave = t >> 6;
    int wr = wave >> 1, wc = wave & 1;
    int brow = blockIdx.x * 128, bcol = blockIdx.y * 128;

    f32x4v acc[4][4] = {};

    for (int kt = 0; kt < 16; ++kt) {
        __syncthreads();
        const _Float16* Ab = Sh2 + ((size_t)kt * 4096 + brow) * 32;
        const _Float16* Bb = Th2 + ((size_t)kt * 4096 + bcol) * 32;
#pragma unroll
        for (int w = 0; w < 2; ++w) {
            int e = w * 2048 + t * 8, row = e >> 5, col = e & 31;
            *(f16x8*)(&As[row * 40 + col]) = *(const f16x8*)(Ab + row * 32 + col);
            *(f16x8*)(&Bs[row * 40 + col]) = *(const f16x8*)(Bb + row * 32 + col);
        }
        __syncthreads();

        f16x8 af[4], bf[4];
#pragma unroll
        for (int m = 0; m < 4; ++m)
            af[m] = *(const f16x8*)(&As[(wr * 64 + m * 16 + (lane & 15)) * 40 + (lane >> 4) * 8]);
#pragma unroll
        for (int n = 0; n < 4; ++n)
            bf[n] = *(const f16x8*)(&Bs[(wc * 64 + n * 16 + (lane & 15)) * 40 + (lane >> 4) * 8]);
#pragma unroll
        for (int m = 0; m < 4; ++m)
#pragma unroll
            for (int n = 0; n < 4; ++n)
                acc[m][n] = __builtin_amdgcn_mfma_f32_16x16x32_f16(af[m], bf[n], acc[m][n], 0, 0, 0);
    }

#pragma unroll
    for (int m = 0; m < 4; ++m) {
#pragma unroll
        for (int n = 0; n < 4; ++n) {
#pragma unroll
            for (int r = 0; r < 4; ++r) {
                int i = brow + wr * 64 + m * 16 + (lane >> 4) * 4 + r;
                int j = bcol + wc * 64 + n * 16 + (lane & 15);
                float sq = ns[i] + nt[j] - 2.0f * acc[m][n][r];
                outC[(size_t)i * N_T + j] = sqrtf(fmaxf(sq, 0.0f));
            }
        }
    }
}

// ---------- cooperative: whole Sinkhorn loop with LDS-resident K, custom barriers ----------
__global__ __launch_bounds__(512, 1) void k_coop(const float* __restrict__ Cd,
                                                 float* __restrict__ W,
                                                 float* __restrict__ part,
                                                 float* __restrict__ v,
                                                 double* __restrict__ lossd,
                                                 int* __restrict__ cnt) {
    extern __shared__ char smem[];
    _Float16* Ksh = (_Float16*)smem;                   // [16][4096] = 128 KB
    float* u_s  = (float*)(smem + 131072);             // 16
    float* wred = (float*)(smem + 131072 + 64);        // [8 waves][16 rows]
    float* cred = (float*)(smem + 131072 + 64 + 512);  // [32][16]

    const int t = threadIdx.x;
    const int lane = t & 63, wave = t >> 6;
    const int b = blockIdx.x;
    const int base = t * 8;                            // 8 cols per thread

    const float* Crow = Cd + (size_t)b * (16 * 4096);

    // load C -> K = exp(-C/8) into LDS (fp16)
#pragma unroll
    for (int i = 0; i < 16; ++i) {
        const float* cp = Crow + i * 4096 + base;
        float4 c0 = *(const float4*)cp;
        float4 c1 = *(const float4*)(cp + 4);
        f16x8 h;
        h[0] = (_Float16)__expf(c0.x * -0.125f);
        h[1] = (_Float16)__expf(c0.y * -0.125f);
        h[2] = (_Float16)__expf(c0.z * -0.125f);
        h[3] = (_Float16)__expf(c0.w * -0.125f);
        h[4] = (_Float16)__expf(c1.x * -0.125f);
        h[5] = (_Float16)__expf(c1.y * -0.125f);
        h[6] = (_Float16)__expf(c1.z * -0.125f);
        h[7] = (_Float16)__expf(c1.w * -0.125f);
        *(f16x8*)(Ksh + i * 4096 + base) = h;
    }
    __syncthreads();

    for (int it = 0; it < 10; ++it) {
        // ---- row pass: u = a / (K v) ----
        float4 v0 = *(const float4*)(v + base);
        float4 v1 = *(const float4*)(v + base + 4);
        float vf[8] = {v0.x, v0.y, v0.z, v0.w, v1.x, v1.y, v1.z, v1.w};
#pragma unroll
        for (int i = 0; i < 16; ++i) {
            f16x8 k8 = *(const f16x8*)(Ksh + i * 4096 + base);
            float p = 0.f;
#pragma unroll
            for (int c = 0; c < 8; ++c) p += (float)k8[c] * vf[c];
#pragma unroll
            for (int m = 32; m; m >>= 1) p += __shfl_xor(p, m);
            if (lane == 0) wred[wave * 16 + i] = p;
        }
        __syncthreads();
        if (t < 16) {
            float s = 0.f;
#pragma unroll
            for (int w = 0; w < 8; ++w) s += wred[w * 16 + t];
            u_s[t] = (1.0f / N_S) / (s + STAB);
        }
        __syncthreads();
        // ---- col pass: per-block column partials ----
        float acc[8] = {0.f,0.f,0.f,0.f,0.f,0.f,0.f,0.f};
#pragma unroll
        for (int i = 0; i < 16; ++i) {
            f16x8 k8 = *(const f16x8*)(Ksh + i * 4096 + base);
            float ui = u_s[i];
#pragma unroll
            for (int c = 0; c < 8; ++c) acc[c] += ui * (float)k8[c];
        }
        float* pp = part + (size_t)b * 4096 + base;
        *(float4*)pp       = make_float4(acc[0], acc[1], acc[2], acc[3]);
        *(float4*)(pp + 4) = make_float4(acc[4], acc[5], acc[6], acc[7]);
        gbar(&cnt[it * 2]);
        // ---- distributed v-reduce: block b owns cols [b*16, b*16+16) ----
        {
            int c = t & 15, p0 = t >> 4;               // 32 chunks x 8 partials
            int j = b * 16 + c;
            float s = 0.f;
#pragma unroll
            for (int k = 0; k < 8; ++k)
                s += part[(size_t)(p0 * 8 + k) * 4096 + j];
            cred[p0 * 16 + c] = s;
        }
        __syncthreads();
        if (t < 16) {
            float s2 = 0.f;
#pragma unroll
            for (int k = 0; k < 32; ++k) s2 += cred[k * 16 + t];
            v[b * 16 + t] = (1.0f / N_T) / (s2 + STAB);
        }
        gbar(&cnt[it * 2 + 1]);
    }

    // ---- fused final: W = u*K*v, loss += sum(W*C), C recovered as -8*ln(K) ----
    float4 v0 = *(const float4*)(v + base);
    float4 v1 = *(const float4*)(v + base + 4);
    float vf[8] = {v0.x, v0.y, v0.z, v0.w, v1.x, v1.y, v1.z, v1.w};
    float lacc = 0.f;
    const float NEG8LN2 = -5.5451774444795623f;        // -8*ln(2)
#pragma unroll
    for (int i = 0; i < 16; ++i) {
        f16x8 k8 = *(const f16x8*)(Ksh + i * 4096 + base);
        float ui = u_s[i];
        float w[8];
#pragma unroll
        for (int c = 0; c < 8; ++c) {
            float kf = (float)k8[c];
            float wc = ui * kf * vf[c];
            w[c] = wc;
            lacc += wc * (NEG8LN2 * __log2f(kf));
        }
        float* wp = W + (size_t)(b * 16 + i) * 4096 + base;
        *(float4*)wp       = make_float4(w[0], w[1], w[2], w[3]);
        *(float4*)(wp + 4) = make_float4(w[4], w[5], w[6], w[7]);
    }
#pragma unroll
    for (int m = 32; m; m >>= 1) lacc += __shfl_xor(lacc, m);
    if (lane == 0) wred[wave] = lacc;
    __syncthreads();
    if (t == 0) {
        float s = 0.f;
#pragma unroll
        for (int w = 0; w < 8; ++w) s += wred[w];
        atomicAdd(lossd, (double)s);
    }
}

__global__ void k_loss(const double* __restrict__ lossd, float* __restrict__ out0) {
    *out0 = (float)(*lossd / ((double)N_S * (double)N_T));
}

// ---------- fp32 K = exp(-C/8) (coop-fail fallback) ----------
__global__ __launch_bounds__(256) void k_k32(const float* __restrict__ Cd, float* __restrict__ K) {
    size_t i = ((size_t)blockIdx.x * 256 + threadIdx.x) * 4;
    float4 c = *(const float4*)(Cd + i);
    float4 k;
    k.x = __expf(c.x * -0.125f);
    k.y = __expf(c.y * -0.125f);
    k.z = __expf(c.z * -0.125f);
    k.w = __expf(c.w * -0.125f);
    *(float4*)(K + i) = k;
}

// ================= round-1 proven kernels (fallbacks) =================
template<int MODE>
__global__ __launch_bounds__(256) void k_gemm(const float* __restrict__ S, const float* __restrict__ T,
                                              const float* __restrict__ ns, const float* __restrict__ nt,
                                              float* __restrict__ outK, float* __restrict__ outC) {
    __shared__ _Float16 As[128 * 40];
    __shared__ _Float16 Bs[128 * 40];
    int t = threadIdx.x;
    int lane = t & 63, wave = t >> 6;
    int wr = wave >> 1, wc = wave & 1;
    int brow = blockIdx.x * 128, bcol = blockIdx.y * 128;

    f32x4v acc[4][4] = {};

    for (int kt = 0; kt < DIM; kt += 32) {
        __syncthreads();
#pragma unroll
        for (int w = 0; w < 4; ++w) {
            int e = w * 1024 + t * 4;
            int row = e >> 5, col = e & 31;
            float4 a = *(const float4*)(S + (size_t)(brow + row) * DIM + kt + col);
            f16x4 ah = { (_Float16)a.x, (_Float16)a.y, (_Float16)a.z, (_Float16)a.w };
            *(f16x4*)(&As[row * 40 + col]) = ah;
            float4 b = *(const float4*)(T + (size_t)(bcol + row) * DIM + kt + col);
            f16x4 bh = { (_Float16)b.x, (_Float16)b.y, (_Float16)b.z, (_Float16)b.w };
            *(f16x4*)(&Bs[row * 40 + col]) = bh;
        }
        __syncthreads();

        f16x8 af[4], bf[4];
#pragma unroll
        for (int m = 0; m < 4; ++m)
            af[m] = *(const f16x8*)(&As[(wr * 64 + m * 16 + (lane & 15)) * 40 + (lane >> 4) * 8]);
#pragma unroll
        for (int n = 0; n < 4; ++n)
            bf[n] = *(const f16x8*)(&Bs[(wc * 64 + n * 16 + (lane & 15)) * 40 + (lane >> 4) * 8]);
#pragma unroll
        for (int m = 0; m < 4; ++m)
#pragma unroll
            for (int n = 0; n < 4; ++n)
                acc[m][n] = __builtin_amdgcn_mfma_f32_16x16x32_f16(af[m], bf[n], acc[m][n], 0, 0, 0);
    }

#pragma unroll
    for (int m = 0; m < 4; ++m) {
#pragma unroll
        for (int n = 0; n < 4; ++n) {
#pragma unroll
            for (int r = 0; r < 4; ++r) {
                int i = brow + wr * 64 + m * 16 + (lane >> 4) * 4 + r;
                int j = bcol + wc * 64 + n * 16 + (lane & 15);
                float sq = ns[i] + nt[j] - 2.0f * acc[m][n][r];
                float c = sqrtf(fmaxf(sq, 0.0f));
                size_t idx = (size_t)i * N_T + j;
                outC[idx] = c;
                if constexpr (MODE == 0) outK[idx] = __expf(-c * 0.125f);
            }
        }
    }
}

__global__ __launch_bounds__(256) void k_rowmv(const float* __restrict__ Kd,
                                               const float* __restrict__ v, float* __restrict__ u) {
    __shared__ float vl[4096];
    int t = threadIdx.x;
#pragma unroll
    for (int c = 0; c < 16; ++c) vl[c * 256 + t] = v[c * 256 + t];
    __syncthreads();
    int lane = t & 63, wave = t >> 6;
    int row = blockIdx.x * 4 + wave;
    const float* Kr = Kd + (size_t)row * N_T;
    float dot = 0.f;
#pragma unroll 8
    for (int c = 0; c < 64; ++c) {
        int j = c * 64 + lane;
        dot += Kr[j] * vl[j];
    }
#pragma unroll
    for (int m = 32; m; m >>= 1) dot += __shfl_xor(dot, m);
    if (lane == 0) u[row] = (1.0f / N_S) / (dot + STAB);
}

__global__ __launch_bounds__(256) void k_colmv(const float* __restrict__ Kd,
                                               const float* __restrict__ u, float* __restrict__ vacc) {
    __shared__ float ul[64];
    int t = threadIdx.x;
    int rc = blockIdx.y;
    if (t < 64) ul[t] = u[rc * 64 + t];
    __syncthreads();
    int j = blockIdx.x * 256 + t;
    const float* Kp = Kd + (size_t)(rc * 64) * N_T + j;
    float acc = 0.f;
#pragma unroll 8
    for (int r = 0; r < 64; ++r) acc += Kp[(size_t)r * N_T] * ul[r];
    atomicAdd(&vacc[j], acc);
}

__global__ void k_vfin(float* v, float* vacc) {
    int j = blockIdx.x * 256 + threadIdx.x;
    v[j] = (1.0f / N_T) / (vacc[j] + STAB);
    vacc[j] = 0.f;
}

__global__ __launch_bounds__(256) void k_final(float* __restrict__ Kd, const float* __restrict__ Cd,
                                               const float* __restrict__ u, const float* __restrict__ v,
                                               double* __restrict__ lossd) {
    int t = threadIdx.x;
    int row = blockIdx.x;
    float ui = u[row];
    float lacc = 0.f;
#pragma unroll 4
    for (int c = 0; c < 16; ++c) {
        int j = c * 256 + t;
        size_t idx = (size_t)row * N_T + j;
        float w = ui * Kd[idx] * v[j];
        Kd[idx] = w;
        lacc += w * Cd[idx];
    }
#pragma unroll
    for (int m = 32; m; m >>= 1) lacc += __shfl_xor(lacc, m);
    __shared__ float wsum[4];
    int lane = t & 63, wave = t >> 6;
    if (lane == 0) wsum[wave] = lacc;
    __syncthreads();
    if (t == 0) atomicAdd(lossd, (double)(wsum[0] + wsum[1] + wsum[2] + wsum[3]));
}

// =====================================================================
extern "C" void kernel_launch(void* const* d_in, const int* in_sizes, int n_in,
                              void* d_out, int out_size, void* d_ws, size_t ws_size,
                              hipStream_t stream) {
    const float* S = (const float*)d_in[0];
    const float* T = (const float*)d_in[1];
    float* out = (float*)d_out;
    float* outCoup = out + 1;
    float* outC = out + 1 + (size_t)N_S * N_T;

    const size_t MB = 1024 * 1024;
    const size_t need = 12 * MB + 96 * 1024;

    if (ws_size >= need) {
        char* wsb = (char*)d_ws;
        _Float16* Sh2 = (_Float16*)wsb;                 // 4 MB, K-tile-blocked
        _Float16* Th2 = (_Float16*)(wsb + 4 * MB);      // 4 MB
        float* partC  = (float*)(wsb + 8 * MB);         // 4 MB [256][4096]
        float* ns = (float*)(wsb + 12 * MB);
        float* nt = ns + 4096;
        float* u  = nt + 4096;
        float* v  = u + 4096;
        float* vacc = v + 4096;
        double* lossd = (double*)(vacc + 4096);
        int* cnt = (int*)(lossd + 1);                   // 32 ints

        k_norms<<<2048, 256, 0, stream>>>((const float4*)S, (const float4*)T, ns, nt);
        k_cvt<<<2048, 256, 0, stream>>>(S, T, Sh2, Th2);
        k_init<<<16, 256, 0, stream>>>(v, vacc, lossd, cnt);
        k_gemm16<<<dim3(32, 32), 256, 0, stream>>>(Sh2, Th2, ns, nt, outC);

        (void)hipFuncSetAttribute((const void*)k_coop,
                                  hipFuncAttributeMaxDynamicSharedMemorySize, COOP_SMEM);
        const float* CdArg = outC; float* WArg = outCoup; float* partArg = partC;
        float* vArg = v; double* ldArg = lossd; int* cntArg = cnt;
        void* args[6] = { &CdArg, &WArg, &partArg, &vArg, &ldArg, &cntArg };
        hipError_t ce = hipLaunchCooperativeKernel((const void*)k_coop, dim3(NBLK), dim3(512),
                                                   args, (unsigned)COOP_SMEM, stream);
        if (ce == hipSuccess) {
            k_loss<<<1, 1, 0, stream>>>(lossd, out);
        } else {
            // coop launch failed: fp32 K in coupling slot + round-1 proven loop
            float* outK = outCoup;
            k_k32<<<16384, 256, 0, stream>>>(outC, outK);
            for (int it = 0; it < 10; ++it) {
                k_rowmv<<<1024, 256, 0, stream>>>(outK, v, u);
                k_colmv<<<dim3(16, 64), 256, 0, stream>>>(outK, u, vacc);
                k_vfin<<<16, 256, 0, stream>>>(v, vacc);
            }
            k_final<<<4096, 256, 0, stream>>>(outK, outC, u, v, lossd);
            k_loss<<<1, 1, 0, stream>>>(lossd, out);
        }
    } else {
        // tiny-ws: round-1 proven fallback end-to-end
        float* outK = outCoup;
        float* ws   = (float*)d_ws;
        float* ns   = ws;
        float* nt   = ws + 4096;
        float* u    = ws + 8192;
        float* v    = ws + 12288;
        float* vacc = ws + 16384;
        double* lossd = (double*)(ws + 20480);
        int* cnt = (int*)(lossd + 1);

        k_norms<<<2048, 256, 0, stream>>>((const float4*)S, (const float4*)T, ns, nt);
        k_init<<<16, 256, 0, stream>>>(v, vacc, lossd, cnt);
        k_gemm<0><<<dim3(32, 32), 256, 0, stream>>>(S, T, ns, nt, outK, outC);
        for (int it = 0; it < 10; ++it) {
            k_rowmv<<<1024, 256, 0, stream>>>(outK, v, u);
            k_colmv<<<dim3(16, 64), 256, 0, stream>>>(outK, u, vacc);
            k_vfin<<<16, 256, 0, stream>>>(v, vacc);
        }
        k_final<<<4096, 256, 0, stream>>>(outK, outC, u, v, lossd);
        k_loss<<<1, 1, 0, stream>>>(lossd, out);
    }
}

// Round 5
// 409.419 us; speedup vs baseline: 2.2229x; 1.5647x over previous
//
#include <hip/hip_runtime.h>
#include <math.h>

// JCPOT Sinkhorn. d_out: [0]=loss, [1..16M]=coupling, [1+16M..]=C.
// Main path (proven round-2 shape, upgraded): fp16-blocked GEMM writes C only;
// per iteration: k_sink2 (K read once: u + col-partials, 4 blocks/CU) + k_vred.
// Final: coupling + loss from Kh with C recovered as -8*ln(K) (no C re-read).
// Global barriers are NOT used: measured ~19-34us/sync on this chip (rounds 3-4).
// Fallback (tiny ws): round-1 proven fp32 pipeline.

#define N_S 4096
#define N_T 4096
#define DIM 512
#define STAB 1e-8f

typedef _Float16 f16x4 __attribute__((ext_vector_type(4)));
typedef _Float16 f16x8 __attribute__((ext_vector_type(8)));
typedef float f32x4v __attribute__((ext_vector_type(4)));

#define SINK_BLOCKS 1024   // 4 rows each; exactly 4 blocks/CU on 256 CUs

// ---------- row squared norms ----------
__global__ __launch_bounds__(256) void k_norms(const float4* __restrict__ S4,
                                               const float4* __restrict__ T4,
                                               float* __restrict__ ns, float* __restrict__ nt) {
    int t = threadIdx.x;
    int lane = t & 63, wave = t >> 6;
    int wid = blockIdx.x * 4 + wave;
    const float4* src; float* dst; int row;
    if (wid < N_S) { src = S4; dst = ns; row = wid; }
    else           { src = T4; dst = nt; row = wid - N_S; }
    float acc = 0.f;
#pragma unroll
    for (int c = 0; c < 2; ++c) {
        float4 x = src[row * 128 + c * 64 + lane];
        acc += x.x*x.x + x.y*x.y + x.z*x.z + x.w*x.w;
    }
#pragma unroll
    for (int m = 32; m; m >>= 1) acc += __shfl_xor(acc, m);
    if (lane == 0) dst[row] = acc;
}

// ---------- fp32 -> fp16 K-tile-blocked convert: dst[k/32][row][k%32] ----------
__global__ __launch_bounds__(256) void k_cvt(const float* __restrict__ S, const float* __restrict__ T,
                                             _Float16* __restrict__ Sh2, _Float16* __restrict__ Th2) {
    int g = blockIdx.x * 256 + threadIdx.x;        // 0..524287
    const float* src; _Float16* dst;
    if (g < 262144) { src = S; dst = Sh2; }
    else            { src = T; dst = Th2; g -= 262144; }
    int row = g >> 6, cb = (g & 63) * 8;
    float4 x0 = *(const float4*)(src + (size_t)row * 512 + cb);
    float4 x1 = *(const float4*)(src + (size_t)row * 512 + cb + 4);
    f16x8 h = { (_Float16)x0.x, (_Float16)x0.y, (_Float16)x0.z, (_Float16)x0.w,
                (_Float16)x1.x, (_Float16)x1.y, (_Float16)x1.z, (_Float16)x1.w };
    *(f16x8*)(dst + ((size_t)(cb >> 5) * 4096 + row) * 32 + (cb & 31)) = h;
}

// ---------- init ----------
__global__ void k_init(float* v, float* vacc, double* lossd) {
    int g = blockIdx.x * 256 + threadIdx.x;
    if (g < N_T) { v[g] = 1.0f; vacc[g] = 0.0f; }
    if (g == 0) *lossd = 0.0;
}

// ---------- GEMM from fp16-blocked inputs, writes C only (validated round 4) ----------
__global__ __launch_bounds__(256) void k_gemm16(const _Float16* __restrict__ Sh2,
                                                const _Float16* __restrict__ Th2,
                                                const float* __restrict__ ns,
                                                const float* __restrict__ nt,
                                                float* __restrict__ outC) {
    __shared__ _Float16 As[128 * 40];
    __shared__ _Float16 Bs[128 * 40];
    int t = threadIdx.x;
    int lane = t & 63, wave = t >> 6;
    int wr = wave >> 1, wc = wave & 1;
    int brow = blockIdx.x * 128, bcol = blockIdx.y * 128;

    f32x4v acc[4][4] = {};

    for (int kt = 0; kt < 16; ++kt) {
        __syncthreads();
        const _Float16* Ab = Sh2 + ((size_t)kt * 4096 + brow) * 32;
        const _Float16* Bb = Th2 + ((size_t)kt * 4096 + bcol) * 32;
#pragma unroll
        for (int w = 0; w < 2; ++w) {
            int e = w * 2048 + t * 8, row = e >> 5, col = e & 31;
            *(f16x8*)(&As[row * 40 + col]) = *(const f16x8*)(Ab + row * 32 + col);
            *(f16x8*)(&Bs[row * 40 + col]) = *(const f16x8*)(Bb + row * 32 + col);
        }
        __syncthreads();

        f16x8 af[4], bf[4];
#pragma unroll
        for (int m = 0; m < 4; ++m)
            af[m] = *(const f16x8*)(&As[(wr * 64 + m * 16 + (lane & 15)) * 40 + (lane >> 4) * 8]);
#pragma unroll
        for (int n = 0; n < 4; ++n)
            bf[n] = *(const f16x8*)(&Bs[(wc * 64 + n * 16 + (lane & 15)) * 40 + (lane >> 4) * 8]);
#pragma unroll
        for (int m = 0; m < 4; ++m)
#pragma unroll
            for (int n = 0; n < 4; ++n)
                acc[m][n] = __builtin_amdgcn_mfma_f32_16x16x32_f16(af[m], bf[n], acc[m][n], 0, 0, 0);
    }

#pragma unroll
    for (int m = 0; m < 4; ++m) {
#pragma unroll
        for (int n = 0; n < 4; ++n) {
#pragma unroll
            for (int r = 0; r < 4; ++r) {
                int i = brow + wr * 64 + m * 16 + (lane >> 4) * 4 + r;
                int j = bcol + wc * 64 + n * 16 + (lane & 15);
                float sq = ns[i] + nt[j] - 2.0f * acc[m][n][r];
                outC[(size_t)i * N_T + j] = sqrtf(fmaxf(sq, 0.0f));
            }
        }
    }
}

// ---------- fp16 Kh = exp(-C/8) ----------
__global__ __launch_bounds__(256) void k_kh(const float* __restrict__ Cd, _Float16* __restrict__ Kh) {
    size_t i = ((size_t)blockIdx.x * 256 + threadIdx.x) * 8;
    float4 c0 = *(const float4*)(Cd + i);
    float4 c1 = *(const float4*)(Cd + i + 4);
    f16x8 h;
    h[0] = (_Float16)__expf(c0.x * -0.125f);
    h[1] = (_Float16)__expf(c0.y * -0.125f);
    h[2] = (_Float16)__expf(c0.z * -0.125f);
    h[3] = (_Float16)__expf(c0.w * -0.125f);
    h[4] = (_Float16)__expf(c1.x * -0.125f);
    h[5] = (_Float16)__expf(c1.y * -0.125f);
    h[6] = (_Float16)__expf(c1.z * -0.125f);
    h[7] = (_Float16)__expf(c1.w * -0.125f);
    *(f16x8*)(Kh + i) = h;
}

// ---------- fused iteration: u = a/(Kv) + per-block col partials (K read ONCE) ----------
// 1024 blocks x 256 threads (4 waves), 4 rows/block (one per wave), 32KB LDS.
__global__ __launch_bounds__(256) void k_sink2(const _Float16* __restrict__ Kh,
                                               const float* __restrict__ v,
                                               float* __restrict__ u_out,
                                               float* __restrict__ part) {
    __shared__ _Float16 rows[4][4096];   // 32 KB
    __shared__ float u_s[4];
    int t = threadIdx.x, lane = t & 63, w = t >> 6;
    int row = blockIdx.x * 4 + w;
    const _Float16* Kr = Kh + (size_t)row * N_T;

    // issue all 8 row-chunk loads into registers first (keep them in flight)
    f16x8 kk[8];
#pragma unroll
    for (int it = 0; it < 8; ++it)
        kk[it] = *(const f16x8*)(Kr + it * 512 + lane * 8);

    // dot with v + stage to LDS
    float dot = 0.f;
#pragma unroll
    for (int it = 0; it < 8; ++it) {
        int j0 = it * 512 + lane * 8;
        float4 v0 = *(const float4*)(v + j0);
        float4 v1 = *(const float4*)(v + j0 + 4);
        *(f16x8*)(&rows[w][j0]) = kk[it];
        dot += (float)kk[it][0]*v0.x + (float)kk[it][1]*v0.y
             + (float)kk[it][2]*v0.z + (float)kk[it][3]*v0.w
             + (float)kk[it][4]*v1.x + (float)kk[it][5]*v1.y
             + (float)kk[it][6]*v1.z + (float)kk[it][7]*v1.w;
    }
#pragma unroll
    for (int m = 32; m; m >>= 1) dot += __shfl_xor(dot, m);
    if (lane == 0) {
        float uv = (1.0f / N_S) / (dot + STAB);
        u_s[w] = uv;
        u_out[row] = uv;
    }
    __syncthreads();

    // col partials: 16 cols/thread via ds_read_b64 (2-way bank alias = free)
    float4 acc[4] = {};
#pragma unroll
    for (int s = 0; s < 4; ++s) {
        int jj = t * 4 + s * 1024;
#pragma unroll
        for (int r = 0; r < 4; ++r) {
            f16x4 k4 = *(const f16x4*)(&rows[r][jj]);
            float uu = u_s[r];
            acc[s].x += uu * (float)k4[0];
            acc[s].y += uu * (float)k4[1];
            acc[s].z += uu * (float)k4[2];
            acc[s].w += uu * (float)k4[3];
        }
    }
    float* pb = part + (size_t)blockIdx.x * N_T;
#pragma unroll
    for (int s = 0; s < 4; ++s)
        *(float4*)(pb + t * 4 + s * 1024) = acc[s];
}

// ---------- reduce 1024 partial vectors -> v ----------
__global__ __launch_bounds__(256) void k_vred(const float* __restrict__ part, float* __restrict__ v) {
    __shared__ float sums[256];
    int t = threadIdx.x;
    int c = t & 15, p0 = t >> 4;                   // 16 cols x 16 chunks of 64 partials
    int j = blockIdx.x * 16 + c;
    float acc = 0.f;
#pragma unroll 8
    for (int k = 0; k < 64; ++k)
        acc += part[(size_t)(p0 * 64 + k) * N_T + j];
    sums[t] = acc;
    __syncthreads();
    if (t < 16) {
        float s = 0.f;
#pragma unroll
        for (int c2 = 0; c2 < 16; ++c2) s += sums[c2 * 16 + t];
        v[blockIdx.x * 16 + t] = (1.0f / N_T) / (s + STAB);
    }
}

// ---------- coupling = u*Kh*v + loss, C recovered as -8*ln(Kh) (no C read) ----------
__global__ __launch_bounds__(256) void k_final3(const _Float16* __restrict__ Kh,
                                                const float* __restrict__ u, const float* __restrict__ v,
                                                float* __restrict__ W, double* __restrict__ lossd) {
    int t = threadIdx.x, row = blockIdx.x;
    float ui = u[row];
    float lacc = 0.f;
    const float NEG8LN2 = -5.5451774444795623f;    // -8*ln(2)
    const _Float16* Kr = Kh + (size_t)row * N_T;
    float* Wr = W + (size_t)row * N_T;
#pragma unroll
    for (int cc = 0; cc < 4; ++cc) {
        int j = (cc * 256 + t) * 4;
        f16x4 kk = *(const f16x4*)(Kr + j);
        float4 v4 = *(const float4*)(v + j);
        float4 w4;
        float kf0 = (float)kk[0], kf1 = (float)kk[1], kf2 = (float)kk[2], kf3 = (float)kk[3];
        w4.x = ui * kf0 * v4.x;
        w4.y = ui * kf1 * v4.y;
        w4.z = ui * kf2 * v4.z;
        w4.w = ui * kf3 * v4.w;
        *(float4*)(Wr + j) = w4;
        lacc += w4.x * (NEG8LN2 * __log2f(kf0)) + w4.y * (NEG8LN2 * __log2f(kf1))
              + w4.z * (NEG8LN2 * __log2f(kf2)) + w4.w * (NEG8LN2 * __log2f(kf3));
    }
#pragma unroll
    for (int m = 32; m; m >>= 1) lacc += __shfl_xor(lacc, m);
    __shared__ float wsum[4];
    int lane = t & 63, wave = t >> 6;
    if (lane == 0) wsum[wave] = lacc;
    __syncthreads();
    if (t == 0) atomicAdd(lossd, (double)(wsum[0] + wsum[1] + wsum[2] + wsum[3]));
}

__global__ void k_loss(const double* __restrict__ lossd, float* __restrict__ out0) {
    *out0 = (float)(*lossd / ((double)N_S * (double)N_T));
}

// ================= round-1 proven kernels (tiny-ws fallback) =================
__global__ __launch_bounds__(256) void k_gemm0(const float* __restrict__ S, const float* __restrict__ T,
                                               const float* __restrict__ ns, const float* __restrict__ nt,
                                               float* __restrict__ outK, float* __restrict__ outC) {
    __shared__ _Float16 As[128 * 40];
    __shared__ _Float16 Bs[128 * 40];
    int t = threadIdx.x;
    int lane = t & 63, wave = t >> 6;
    int wr = wave >> 1, wc = wave & 1;
    int brow = blockIdx.x * 128, bcol = blockIdx.y * 128;

    f32x4v acc[4][4] = {};

    for (int kt = 0; kt < DIM; kt += 32) {
        __syncthreads();
#pragma unroll
        for (int w = 0; w < 4; ++w) {
            int e = w * 1024 + t * 4;
            int row = e >> 5, col = e & 31;
            float4 a = *(const float4*)(S + (size_t)(brow + row) * DIM + kt + col);
            f16x4 ah = { (_Float16)a.x, (_Float16)a.y, (_Float16)a.z, (_Float16)a.w };
            *(f16x4*)(&As[row * 40 + col]) = ah;
            float4 b = *(const float4*)(T + (size_t)(bcol + row) * DIM + kt + col);
            f16x4 bh = { (_Float16)b.x, (_Float16)b.y, (_Float16)b.z, (_Float16)b.w };
            *(f16x4*)(&Bs[row * 40 + col]) = bh;
        }
        __syncthreads();

        f16x8 af[4], bf[4];
#pragma unroll
        for (int m = 0; m < 4; ++m)
            af[m] = *(const f16x8*)(&As[(wr * 64 + m * 16 + (lane & 15)) * 40 + (lane >> 4) * 8]);
#pragma unroll
        for (int n = 0; n < 4; ++n)
            bf[n] = *(const f16x8*)(&Bs[(wc * 64 + n * 16 + (lane & 15)) * 40 + (lane >> 4) * 8]);
#pragma unroll
        for (int m = 0; m < 4; ++m)
#pragma unroll
            for (int n = 0; n < 4; ++n)
                acc[m][n] = __builtin_amdgcn_mfma_f32_16x16x32_f16(af[m], bf[n], acc[m][n], 0, 0, 0);
    }

#pragma unroll
    for (int m = 0; m < 4; ++m) {
#pragma unroll
        for (int n = 0; n < 4; ++n) {
#pragma unroll
            for (int r = 0; r < 4; ++r) {
                int i = brow + wr * 64 + m * 16 + (lane >> 4) * 4 + r;
                int j = bcol + wc * 64 + n * 16 + (lane & 15);
                float sq = ns[i] + nt[j] - 2.0f * acc[m][n][r];
                float c = sqrtf(fmaxf(sq, 0.0f));
                size_t idx = (size_t)i * N_T + j;
                outC[idx] = c;
                outK[idx] = __expf(-c * 0.125f);
            }
        }
    }
}

__global__ __launch_bounds__(256) void k_rowmv(const float* __restrict__ Kd,
                                               const float* __restrict__ v, float* __restrict__ u) {
    __shared__ float vl[4096];
    int t = threadIdx.x;
#pragma unroll
    for (int c = 0; c < 16; ++c) vl[c * 256 + t] = v[c * 256 + t];
    __syncthreads();
    int lane = t & 63, wave = t >> 6;
    int row = blockIdx.x * 4 + wave;
    const float* Kr = Kd + (size_t)row * N_T;
    float dot = 0.f;
#pragma unroll 8
    for (int c = 0; c < 64; ++c) {
        int j = c * 64 + lane;
        dot += Kr[j] * vl[j];
    }
#pragma unroll
    for (int m = 32; m; m >>= 1) dot += __shfl_xor(dot, m);
    if (lane == 0) u[row] = (1.0f / N_S) / (dot + STAB);
}

__global__ __launch_bounds__(256) void k_colmv(const float* __restrict__ Kd,
                                               const float* __restrict__ u, float* __restrict__ vacc) {
    __shared__ float ul[64];
    int t = threadIdx.x;
    int rc = blockIdx.y;
    if (t < 64) ul[t] = u[rc * 64 + t];
    __syncthreads();
    int j = blockIdx.x * 256 + t;
    const float* Kp = Kd + (size_t)(rc * 64) * N_T + j;
    float acc = 0.f;
#pragma unroll 8
    for (int r = 0; r < 64; ++r) acc += Kp[(size_t)r * N_T] * ul[r];
    atomicAdd(&vacc[j], acc);
}

__global__ void k_vfin(float* v, float* vacc) {
    int j = blockIdx.x * 256 + threadIdx.x;
    v[j] = (1.0f / N_T) / (vacc[j] + STAB);
    vacc[j] = 0.f;
}

__global__ __launch_bounds__(256) void k_final(float* __restrict__ Kd, const float* __restrict__ Cd,
                                               const float* __restrict__ u, const float* __restrict__ v,
                                               double* __restrict__ lossd) {
    int t = threadIdx.x;
    int row = blockIdx.x;
    float ui = u[row];
    float lacc = 0.f;
#pragma unroll 4
    for (int c = 0; c < 16; ++c) {
        int j = c * 256 + t;
        size_t idx = (size_t)row * N_T + j;
        float w = ui * Kd[idx] * v[j];
        Kd[idx] = w;
        lacc += w * Cd[idx];
    }
#pragma unroll
    for (int m = 32; m; m >>= 1) lacc += __shfl_xor(lacc, m);
    __shared__ float wsum[4];
    int lane = t & 63, wave = t >> 6;
    if (lane == 0) wsum[wave] = lacc;
    __syncthreads();
    if (t == 0) atomicAdd(lossd, (double)(wsum[0] + wsum[1] + wsum[2] + wsum[3]));
}

// =====================================================================
extern "C" void kernel_launch(void* const* d_in, const int* in_sizes, int n_in,
                              void* d_out, int out_size, void* d_ws, size_t ws_size,
                              hipStream_t stream) {
    const float* S = (const float*)d_in[0];
    const float* T = (const float*)d_in[1];
    float* out = (float*)d_out;
    float* outCoup = out + 1;
    float* outC = out + 1 + (size_t)N_S * N_T;

    const size_t MB = 1024 * 1024;
    // main ws layout: Sh2 4MB | Th2 4MB | Kh 32MB | part 16MB | scalars
    const size_t need = 56 * MB + 96 * 1024;

    if (ws_size >= need) {
        char* wsb = (char*)d_ws;
        _Float16* Sh2 = (_Float16*)wsb;                 // 4 MB (K-tile-blocked fp16 S)
        _Float16* Th2 = (_Float16*)(wsb + 4 * MB);      // 4 MB
        _Float16* Kh  = (_Float16*)(wsb + 8 * MB);      // 32 MB
        float* part   = (float*)(wsb + 40 * MB);        // 16 MB [1024][4096]
        float* ns = (float*)(wsb + 56 * MB);
        float* nt = ns + 4096;
        float* u  = nt + 4096;
        float* v  = u + 4096;
        float* vacc = v + 4096;
        double* lossd = (double*)(vacc + 4096);

        k_norms<<<2048, 256, 0, stream>>>((const float4*)S, (const float4*)T, ns, nt);
        k_cvt<<<2048, 256, 0, stream>>>(S, T, Sh2, Th2);
        k_init<<<16, 256, 0, stream>>>(v, vacc, lossd);
        k_gemm16<<<dim3(32, 32), 256, 0, stream>>>(Sh2, Th2, ns, nt, outC);
        k_kh<<<8192, 256, 0, stream>>>(outC, Kh);
        for (int it = 0; it < 10; ++it) {
            k_sink2<<<SINK_BLOCKS, 256, 0, stream>>>(Kh, v, u, part);
            k_vred<<<256, 256, 0, stream>>>(part, v);
        }
        k_final3<<<4096, 256, 0, stream>>>(Kh, u, v, outCoup, lossd);
        k_loss<<<1, 1, 0, stream>>>(lossd, out);
    } else {
        // tiny-ws: round-1 proven fallback end-to-end (fp32 K staged in coupling slot)
        float* outK = outCoup;
        float* ws   = (float*)d_ws;
        float* ns   = ws;
        float* nt   = ws + 4096;
        float* u    = ws + 8192;
        float* v    = ws + 12288;
        float* vacc = ws + 16384;
        double* lossd = (double*)(ws + 20480);

        k_norms<<<2048, 256, 0, stream>>>((const float4*)S, (const float4*)T, ns, nt);
        k_init<<<16, 256, 0, stream>>>(v, vacc, lossd);
        k_gemm0<<<dim3(32, 32), 256, 0, stream>>>(S, T, ns, nt, outK, outC);
        for (int it = 0; it < 10; ++it) {
            k_rowmv<<<1024, 256, 0, stream>>>(outK, v, u);
            k_colmv<<<dim3(16, 64), 256, 0, stream>>>(outK, u, vacc);
            k_vfin<<<16, 256, 0, stream>>>(v, vacc);
        }
        k_final<<<4096, 256, 0, stream>>>(outK, outC, u, v, lossd);
        k_loss<<<1, 1, 0, stream>>>(lossd, out);
    }
}

// Round 6
// 388.541 us; speedup vs baseline: 2.3424x; 1.0537x over previous
//
#include <hip/hip_runtime.h>
#include <math.h>

// JCPOT Sinkhorn. d_out: [0]=loss, [1..16M]=coupling, [1+16M..]=C.
// Round 6: gemm epilogue LDS-transposed -> coalesced C + fused fp16 Kh store
// (k_kh pass eliminated); vred coalesced (128B groups); norms+cvt fused.
// sink2 loop unchanged (proven round 5). No global barriers (20us/sync measured).
// Fallback (tiny ws): round-1 proven fp32 pipeline.

#define N_S 4096
#define N_T 4096
#define DIM 512
#define STAB 1e-8f
#define PART_STRIDE 4112   // 4096 + 16 pad: rotate L2 channels across partial rows

typedef _Float16 f16x4 __attribute__((ext_vector_type(4)));
typedef _Float16 f16x8 __attribute__((ext_vector_type(8)));
typedef float f32x4v __attribute__((ext_vector_type(4)));

#define SINK_BLOCKS 1024   // 4 rows each; 4 blocks/CU

// ---------- fused: row norms + fp32->fp16 K-tile-blocked convert ----------
// wave per row: lane covers cols lane*8..lane*8+7
__global__ __launch_bounds__(256) void k_prep(const float* __restrict__ S, const float* __restrict__ T,
                                              _Float16* __restrict__ Sh2, _Float16* __restrict__ Th2,
                                              float* __restrict__ ns, float* __restrict__ nt) {
    int t = threadIdx.x, lane = t & 63, wave = t >> 6;
    int wid = blockIdx.x * 4 + wave;               // 0..8191
    const float* src; _Float16* dst; float* ndst; int row;
    if (wid < N_S) { src = S; dst = Sh2; ndst = ns; row = wid; }
    else           { src = T; dst = Th2; ndst = nt; row = wid - N_S; }
    int cb = lane * 8;
    float4 x0 = *(const float4*)(src + (size_t)row * DIM + cb);
    float4 x1 = *(const float4*)(src + (size_t)row * DIM + cb + 4);
    float acc = x0.x*x0.x + x0.y*x0.y + x0.z*x0.z + x0.w*x0.w
              + x1.x*x1.x + x1.y*x1.y + x1.z*x1.z + x1.w*x1.w;
#pragma unroll
    for (int m = 32; m; m >>= 1) acc += __shfl_xor(acc, m);
    if (lane == 0) ndst[row] = acc;
    f16x8 h = { (_Float16)x0.x, (_Float16)x0.y, (_Float16)x0.z, (_Float16)x0.w,
                (_Float16)x1.x, (_Float16)x1.y, (_Float16)x1.z, (_Float16)x1.w };
    *(f16x8*)(dst + ((size_t)(cb >> 5) * 4096 + row) * 32 + (cb & 31)) = h;
}

// ---------- init ----------
__global__ void k_init(float* v, double* lossd) {
    int g = blockIdx.x * 256 + threadIdx.x;
    if (g < N_T) v[g] = 1.0f;
    if (g == 0) *lossd = 0.0;
}

// ---------- GEMM (f16 MFMA, blocked inputs): coalesced C + fused fp16 Kh ----------
__global__ __launch_bounds__(256) void k_gemm16b(const _Float16* __restrict__ Sh2,
                                                 const _Float16* __restrict__ Th2,
                                                 const float* __restrict__ ns,
                                                 const float* __restrict__ nt,
                                                 float* __restrict__ outC,
                                                 _Float16* __restrict__ Kh) {
    __shared__ _Float16 As[128 * 40];
    __shared__ _Float16 Bs[128 * 40];
    __shared__ float eps[4][16 * 68];              // per-wave transpose buffer (68 = pad)
    int t = threadIdx.x;
    int lane = t & 63, wave = t >> 6;
    int wr = wave >> 1, wc = wave & 1;
    int brow = blockIdx.x * 128, bcol = blockIdx.y * 128;

    f32x4v acc[4][4] = {};

    for (int kt = 0; kt < 16; ++kt) {
        __syncthreads();
        const _Float16* Ab = Sh2 + ((size_t)kt * 4096 + brow) * 32;
        const _Float16* Bb = Th2 + ((size_t)kt * 4096 + bcol) * 32;
#pragma unroll
        for (int w = 0; w < 2; ++w) {
            int e = w * 2048 + t * 8, row = e >> 5, col = e & 31;
            *(f16x8*)(&As[row * 40 + col]) = *(const f16x8*)(Ab + row * 32 + col);
            *(f16x8*)(&Bs[row * 40 + col]) = *(const f16x8*)(Bb + row * 32 + col);
        }
        __syncthreads();

        f16x8 af[4], bf[4];
#pragma unroll
        for (int m = 0; m < 4; ++m)
            af[m] = *(const f16x8*)(&As[(wr * 64 + m * 16 + (lane & 15)) * 40 + (lane >> 4) * 8]);
#pragma unroll
        for (int n = 0; n < 4; ++n)
            bf[n] = *(const f16x8*)(&Bs[(wc * 64 + n * 16 + (lane & 15)) * 40 + (lane >> 4) * 8]);
#pragma unroll
        for (int m = 0; m < 4; ++m)
#pragma unroll
            for (int n = 0; n < 4; ++n)
                acc[m][n] = __builtin_amdgcn_mfma_f32_16x16x32_f16(af[m], bf[n], acc[m][n], 0, 0, 0);
    }

    // Epilogue: per m, transpose wave's 16x64 f32 tile through LDS, then
    // write C (float4, 256B/16-lane group) and Kh (f16x4, 128B/group).
    float* my = &eps[wave][0];
#pragma unroll
    for (int m = 0; m < 4; ++m) {
#pragma unroll
        for (int n = 0; n < 4; ++n)
#pragma unroll
            for (int r = 0; r < 4; ++r)
                my[((lane >> 4) * 4 + r) * 68 + n * 16 + (lane & 15)] = acc[m][n][r];
        __syncthreads();                            // uniform; orders LDS within wave too
#pragma unroll
        for (int rep = 0; rep < 4; ++rep) {
            int rr = (lane >> 4) + rep * 4;         // 0..15
            int cc = (lane & 15) * 4;               // 0..63
            float4 d = *(float4*)(my + rr * 68 + cc);
            int i = brow + wr * 64 + m * 16 + rr;
            int j = bcol + wc * 64 + cc;
            float nsi = ns[i];
            float4 nt4 = *(const float4*)(nt + j);
            float4 c4;
            c4.x = sqrtf(fmaxf(nsi + nt4.x - 2.0f * d.x, 0.0f));
            c4.y = sqrtf(fmaxf(nsi + nt4.y - 2.0f * d.y, 0.0f));
            c4.z = sqrtf(fmaxf(nsi + nt4.z - 2.0f * d.z, 0.0f));
            c4.w = sqrtf(fmaxf(nsi + nt4.w - 2.0f * d.w, 0.0f));
            *(float4*)(outC + (size_t)i * N_T + j) = c4;
            f16x4 kh4 = { (_Float16)__expf(c4.x * -0.125f),
                          (_Float16)__expf(c4.y * -0.125f),
                          (_Float16)__expf(c4.z * -0.125f),
                          (_Float16)__expf(c4.w * -0.125f) };
            *(f16x4*)(Kh + (size_t)i * N_T + j) = kh4;
        }
        __syncthreads();                            // reads done before next m overwrites
    }
}

// ---------- fused iteration: u = a/(Kv) + per-block col partials (K read ONCE) ----------
__global__ __launch_bounds__(256) void k_sink2(const _Float16* __restrict__ Kh,
                                               const float* __restrict__ v,
                                               float* __restrict__ u_out,
                                               float* __restrict__ part) {
    __shared__ _Float16 rows[4][4096];   // 32 KB
    __shared__ float u_s[4];
    int t = threadIdx.x, lane = t & 63, w = t >> 6;
    int row = blockIdx.x * 4 + w;
    const _Float16* Kr = Kh + (size_t)row * N_T;

    f16x8 kk[8];
#pragma unroll
    for (int it = 0; it < 8; ++it)
        kk[it] = *(const f16x8*)(Kr + it * 512 + lane * 8);

    float dot = 0.f;
#pragma unroll
    for (int it = 0; it < 8; ++it) {
        int j0 = it * 512 + lane * 8;
        float4 v0 = *(const float4*)(v + j0);
        float4 v1 = *(const float4*)(v + j0 + 4);
        *(f16x8*)(&rows[w][j0]) = kk[it];
        dot += (float)kk[it][0]*v0.x + (float)kk[it][1]*v0.y
             + (float)kk[it][2]*v0.z + (float)kk[it][3]*v0.w
             + (float)kk[it][4]*v1.x + (float)kk[it][5]*v1.y
             + (float)kk[it][6]*v1.z + (float)kk[it][7]*v1.w;
    }
#pragma unroll
    for (int m = 32; m; m >>= 1) dot += __shfl_xor(dot, m);
    if (lane == 0) {
        float uv = (1.0f / N_S) / (dot + STAB);
        u_s[w] = uv;
        u_out[row] = uv;
    }
    __syncthreads();

    float4 acc[4] = {};
#pragma unroll
    for (int s = 0; s < 4; ++s) {
        int jj = t * 4 + s * 1024;
#pragma unroll
        for (int r = 0; r < 4; ++r) {
            f16x4 k4 = *(const f16x4*)(&rows[r][jj]);
            float uu = u_s[r];
            acc[s].x += uu * (float)k4[0];
            acc[s].y += uu * (float)k4[1];
            acc[s].z += uu * (float)k4[2];
            acc[s].w += uu * (float)k4[3];
        }
    }
    float* pb = part + (size_t)blockIdx.x * PART_STRIDE;
#pragma unroll
    for (int s = 0; s < 4; ++s)
        *(float4*)(pb + t * 4 + s * 1024) = acc[s];
}

// ---------- reduce 1024 partial vectors -> v (coalesced: 128B per 8-thread group) ----------
__global__ __launch_bounds__(256) void k_vred2(const float* __restrict__ part, float* __restrict__ v) {
    __shared__ float red[32][32];
    int t = threadIdx.x;
    int tj = t & 7, tk = t >> 3;                   // 8 col-groups x 32 k-groups
    int j = blockIdx.x * 32 + tj * 4;
    float4 a = {0.f, 0.f, 0.f, 0.f};
#pragma unroll 8
    for (int k = 0; k < 32; ++k) {
        const float* pp = part + (size_t)(tk * 32 + k) * PART_STRIDE + j;
        float4 p4 = *(const float4*)pp;
        a.x += p4.x; a.y += p4.y; a.z += p4.z; a.w += p4.w;
    }
    *(float4*)(&red[tk][tj * 4]) = a;
    __syncthreads();
    if (t < 32) {
        float s = 0.f;
#pragma unroll
        for (int k = 0; k < 32; ++k) s += red[k][t];
        v[blockIdx.x * 32 + t] = (1.0f / N_T) / (s + STAB);
    }
}

// ---------- coupling = u*Kh*v + loss, C recovered as -8*ln(Kh) (no C read) ----------
__global__ __launch_bounds__(256) void k_final3(const _Float16* __restrict__ Kh,
                                                const float* __restrict__ u, const float* __restrict__ v,
                                                float* __restrict__ W, double* __restrict__ lossd) {
    int t = threadIdx.x, row = blockIdx.x;
    float ui = u[row];
    float lacc = 0.f;
    const float NEG8LN2 = -5.5451774444795623f;    // -8*ln(2)
    const _Float16* Kr = Kh + (size_t)row * N_T;
    float* Wr = W + (size_t)row * N_T;
#pragma unroll
    for (int cc = 0; cc < 4; ++cc) {
        int j = (cc * 256 + t) * 4;
        f16x4 kk = *(const f16x4*)(Kr + j);
        float4 v4 = *(const float4*)(v + j);
        float4 w4;
        float kf0 = (float)kk[0], kf1 = (float)kk[1], kf2 = (float)kk[2], kf3 = (float)kk[3];
        w4.x = ui * kf0 * v4.x;
        w4.y = ui * kf1 * v4.y;
        w4.z = ui * kf2 * v4.z;
        w4.w = ui * kf3 * v4.w;
        *(float4*)(Wr + j) = w4;
        lacc += w4.x * (NEG8LN2 * __log2f(kf0)) + w4.y * (NEG8LN2 * __log2f(kf1))
              + w4.z * (NEG8LN2 * __log2f(kf2)) + w4.w * (NEG8LN2 * __log2f(kf3));
    }
#pragma unroll
    for (int m = 32; m; m >>= 1) lacc += __shfl_xor(lacc, m);
    __shared__ float wsum[4];
    int lane = t & 63, wave = t >> 6;
    if (lane == 0) wsum[wave] = lacc;
    __syncthreads();
    if (t == 0) atomicAdd(lossd, (double)(wsum[0] + wsum[1] + wsum[2] + wsum[3]));
}

__global__ void k_loss(const double* __restrict__ lossd, float* __restrict__ out0) {
    *out0 = (float)(*lossd / ((double)N_S * (double)N_T));
}

// ================= round-1 proven kernels (tiny-ws fallback) =================
__global__ __launch_bounds__(256) void k_norms(const float4* __restrict__ S4,
                                               const float4* __restrict__ T4,
                                               float* __restrict__ ns, float* __restrict__ nt) {
    int t = threadIdx.x;
    int lane = t & 63, wave = t >> 6;
    int wid = blockIdx.x * 4 + wave;
    const float4* src; float* dst; int row;
    if (wid < N_S) { src = S4; dst = ns; row = wid; }
    else           { src = T4; dst = nt; row = wid - N_S; }
    float acc = 0.f;
#pragma unroll
    for (int c = 0; c < 2; ++c) {
        float4 x = src[row * 128 + c * 64 + lane];
        acc += x.x*x.x + x.y*x.y + x.z*x.z + x.w*x.w;
    }
#pragma unroll
    for (int m = 32; m; m >>= 1) acc += __shfl_xor(acc, m);
    if (lane == 0) dst[row] = acc;
}

__global__ void k_init0(float* v, float* vacc, double* lossd) {
    int g = blockIdx.x * 256 + threadIdx.x;
    if (g < N_T) { v[g] = 1.0f; vacc[g] = 0.0f; }
    if (g == 0) *lossd = 0.0;
}

__global__ __launch_bounds__(256) void k_gemm0(const float* __restrict__ S, const float* __restrict__ T,
                                               const float* __restrict__ ns, const float* __restrict__ nt,
                                               float* __restrict__ outK, float* __restrict__ outC) {
    __shared__ _Float16 As[128 * 40];
    __shared__ _Float16 Bs[128 * 40];
    int t = threadIdx.x;
    int lane = t & 63, wave = t >> 6;
    int wr = wave >> 1, wc = wave & 1;
    int brow = blockIdx.x * 128, bcol = blockIdx.y * 128;

    f32x4v acc[4][4] = {};

    for (int kt = 0; kt < DIM; kt += 32) {
        __syncthreads();
#pragma unroll
        for (int w = 0; w < 4; ++w) {
            int e = w * 1024 + t * 4;
            int row = e >> 5, col = e & 31;
            float4 a = *(const float4*)(S + (size_t)(brow + row) * DIM + kt + col);
            f16x4 ah = { (_Float16)a.x, (_Float16)a.y, (_Float16)a.z, (_Float16)a.w };
            *(f16x4*)(&As[row * 40 + col]) = ah;
            float4 b = *(const float4*)(T + (size_t)(bcol + row) * DIM + kt + col);
            f16x4 bh = { (_Float16)b.x, (_Float16)b.y, (_Float16)b.z, (_Float16)b.w };
            *(f16x4*)(&Bs[row * 40 + col]) = bh;
        }
        __syncthreads();

        f16x8 af[4], bf[4];
#pragma unroll
        for (int m = 0; m < 4; ++m)
            af[m] = *(const f16x8*)(&As[(wr * 64 + m * 16 + (lane & 15)) * 40 + (lane >> 4) * 8]);
#pragma unroll
        for (int n = 0; n < 4; ++n)
            bf[n] = *(const f16x8*)(&Bs[(wc * 64 + n * 16 + (lane & 15)) * 40 + (lane >> 4) * 8]);
#pragma unroll
        for (int m = 0; m < 4; ++m)
#pragma unroll
            for (int n = 0; n < 4; ++n)
                acc[m][n] = __builtin_amdgcn_mfma_f32_16x16x32_f16(af[m], bf[n], acc[m][n], 0, 0, 0);
    }

#pragma unroll
    for (int m = 0; m < 4; ++m) {
#pragma unroll
        for (int n = 0; n < 4; ++n) {
#pragma unroll
            for (int r = 0; r < 4; ++r) {
                int i = brow + wr * 64 + m * 16 + (lane >> 4) * 4 + r;
                int j = bcol + wc * 64 + n * 16 + (lane & 15);
                float sq = ns[i] + nt[j] - 2.0f * acc[m][n][r];
                float c = sqrtf(fmaxf(sq, 0.0f));
                size_t idx = (size_t)i * N_T + j;
                outC[idx] = c;
                outK[idx] = __expf(-c * 0.125f);
            }
        }
    }
}

__global__ __launch_bounds__(256) void k_rowmv(const float* __restrict__ Kd,
                                               const float* __restrict__ v, float* __restrict__ u) {
    __shared__ float vl[4096];
    int t = threadIdx.x;
#pragma unroll
    for (int c = 0; c < 16; ++c) vl[c * 256 + t] = v[c * 256 + t];
    __syncthreads();
    int lane = t & 63, wave = t >> 6;
    int row = blockIdx.x * 4 + wave;
    const float* Kr = Kd + (size_t)row * N_T;
    float dot = 0.f;
#pragma unroll 8
    for (int c = 0; c < 64; ++c) {
        int j = c * 64 + lane;
        dot += Kr[j] * vl[j];
    }
#pragma unroll
    for (int m = 32; m; m >>= 1) dot += __shfl_xor(dot, m);
    if (lane == 0) u[row] = (1.0f / N_S) / (dot + STAB);
}

__global__ __launch_bounds__(256) void k_colmv(const float* __restrict__ Kd,
                                               const float* __restrict__ u, float* __restrict__ vacc) {
    __shared__ float ul[64];
    int t = threadIdx.x;
    int rc = blockIdx.y;
    if (t < 64) ul[t] = u[rc * 64 + t];
    __syncthreads();
    int j = blockIdx.x * 256 + t;
    const float* Kp = Kd + (size_t)(rc * 64) * N_T + j;
    float acc = 0.f;
#pragma unroll 8
    for (int r = 0; r < 64; ++r) acc += Kp[(size_t)r * N_T] * ul[r];
    atomicAdd(&vacc[j], acc);
}

__global__ void k_vfin(float* v, float* vacc) {
    int j = blockIdx.x * 256 + threadIdx.x;
    v[j] = (1.0f / N_T) / (vacc[j] + STAB);
    vacc[j] = 0.f;
}

__global__ __launch_bounds__(256) void k_final(float* __restrict__ Kd, const float* __restrict__ Cd,
                                               const float* __restrict__ u, const float* __restrict__ v,
                                               double* __restrict__ lossd) {
    int t = threadIdx.x;
    int row = blockIdx.x;
    float ui = u[row];
    float lacc = 0.f;
#pragma unroll 4
    for (int c = 0; c < 16; ++c) {
        int j = c * 256 + t;
        size_t idx = (size_t)row * N_T + j;
        float w = ui * Kd[idx] * v[j];
        Kd[idx] = w;
        lacc += w * Cd[idx];
    }
#pragma unroll
    for (int m = 32; m; m >>= 1) lacc += __shfl_xor(lacc, m);
    __shared__ float wsum[4];
    int lane = t & 63, wave = t >> 6;
    if (lane == 0) wsum[wave] = lacc;
    __syncthreads();
    if (t == 0) atomicAdd(lossd, (double)(wsum[0] + wsum[1] + wsum[2] + wsum[3]));
}

// =====================================================================
extern "C" void kernel_launch(void* const* d_in, const int* in_sizes, int n_in,
                              void* d_out, int out_size, void* d_ws, size_t ws_size,
                              hipStream_t stream) {
    const float* S = (const float*)d_in[0];
    const float* T = (const float*)d_in[1];
    float* out = (float*)d_out;
    float* outCoup = out + 1;
    float* outC = out + 1 + (size_t)N_S * N_T;

    const size_t MB = 1024 * 1024;
    // main ws layout: Sh2 4MB | Th2 4MB | Kh 32MB | part 1024*4112*4B (~16.1MB) | scalars
    const size_t PART_BYTES = (size_t)1024 * PART_STRIDE * 4;
    const size_t need = 40 * MB + PART_BYTES + 96 * 1024;

    if (ws_size >= need) {
        char* wsb = (char*)d_ws;
        _Float16* Sh2 = (_Float16*)wsb;                 // 4 MB (K-tile-blocked fp16 S)
        _Float16* Th2 = (_Float16*)(wsb + 4 * MB);      // 4 MB
        _Float16* Kh  = (_Float16*)(wsb + 8 * MB);      // 32 MB
        float* part   = (float*)(wsb + 40 * MB);        // padded partials
        char* tail    = wsb + 40 * MB + PART_BYTES;
        float* ns = (float*)tail;
        float* nt = ns + 4096;
        float* u  = nt + 4096;
        float* v  = u + 4096;
        double* lossd = (double*)(v + 4096);

        k_prep<<<2048, 256, 0, stream>>>(S, T, Sh2, Th2, ns, nt);
        k_init<<<16, 256, 0, stream>>>(v, lossd);
        k_gemm16b<<<dim3(32, 32), 256, 0, stream>>>(Sh2, Th2, ns, nt, outC, Kh);
        for (int it = 0; it < 10; ++it) {
            k_sink2<<<SINK_BLOCKS, 256, 0, stream>>>(Kh, v, u, part);
            k_vred2<<<128, 256, 0, stream>>>(part, v);
        }
        k_final3<<<4096, 256, 0, stream>>>(Kh, u, v, outCoup, lossd);
        k_loss<<<1, 1, 0, stream>>>(lossd, out);
    } else {
        // tiny-ws: round-1 proven fallback end-to-end (fp32 K staged in coupling slot)
        float* outK = outCoup;
        float* ws   = (float*)d_ws;
        float* ns   = ws;
        float* nt   = ws + 4096;
        float* u    = ws + 8192;
        float* v    = ws + 12288;
        float* vacc = ws + 16384;
        double* lossd = (double*)(ws + 20480);

        k_norms<<<2048, 256, 0, stream>>>((const float4*)S, (const float4*)T, ns, nt);
        k_init0<<<16, 256, 0, stream>>>(v, vacc, lossd);
        k_gemm0<<<dim3(32, 32), 256, 0, stream>>>(S, T, ns, nt, outK, outC);
        for (int it = 0; it < 10; ++it) {
            k_rowmv<<<1024, 256, 0, stream>>>(outK, v, u);
            k_colmv<<<dim3(16, 64), 256, 0, stream>>>(outK, u, vacc);
            k_vfin<<<16, 256, 0, stream>>>(v, vacc);
        }
        k_final<<<4096, 256, 0, stream>>>(outK, outC, u, v, lossd);
        k_loss<<<1, 1, 0, stream>>>(lossd, out);
    }
}